// Round 1
// baseline (1336.360 us; speedup 1.0000x reference)
//
#include <hip/hip_runtime.h>
#include <math.h>

#define FLT_BIG 3.0e38f
constexpr int HMAX = 24;   // max per-list k (k0,k1 in [8,24])

// ---------------------------------------------------------------------------
// K1: KNN. One block = 32 queries of one sample. Thread t: query t>>3,
// list (t>>2)&1, slice t&3 (1024 candidates each). Per-thread LDS max-heap,
// then insertion-sort + 4-way merge; emits feat(resi,dist) float4 and newp.
// ---------------------------------------------------------------------------
__global__ __launch_bounds__(256) void knn_kernel(
    const float* __restrict__ p0, const float* __restrict__ p1,
    const float* __restrict__ wt, const int* __restrict__ perm,
    float4* __restrict__ feat, float4* __restrict__ newp, int N)
{
    __shared__ float sd[HMAX * 256];
    __shared__ unsigned short si[HMAX * 256];
    const int t = threadIdx.x;
    const int nchunks = N >> 5;
    const int b = blockIdx.x / nchunks;
    const int nbase = (blockIdx.x - b * nchunks) << 5;
    const int ql = t >> 3, list = (t >> 2) & 1, slice = t & 3;
    const int n = nbase + ql;

    const float wt0 = wt[b * 2];
    const int N0 = (int)(N * wt0);        // exact: N * f32 is a pow2 scale
    const int k0 = (int)(32 * wt0);
    const int kk = list ? (32 - k0) : k0;

    // query coords (queries are permuted members of p0/p1)
    int j; const float* src;
    if (n < N0) { j = perm[(b * 2) * N + n];            src = p0; }
    else        { j = perm[(b * 2 + 1) * N + (n - N0)]; src = p1; }
    const float qx = src[(b * 3) * N + j];
    const float qy = src[(b * 3 + 1) * N + j];
    const float qz = src[(b * 3 + 2) * N + j];
    const float qq = qx * qx + qy * qy + qz * qz;

    const float* rb = (list ? p1 : p0) + (b * 3) * N;

    // init heap with +inf placeholders (all evicted: 1024 >= kk)
    for (int e = 0; e < kk; ++e) sd[e * 256 + t] = FLT_BIG;
    float thr = FLT_BIG;

    const int msz = N >> 2;
    const int mbase = slice * msz;
    for (int m = mbase; m < mbase + msz; ++m) {
        const float px = rb[m], py = rb[N + m], pz = rb[2 * N + m];
        const float pp = px * px + py * py + pz * pz;
        const float dt = qx * px + qy * py + qz * pz;
        const float d = (qq + pp) - 2.f * dt;   // reference's d2 formula
        if (d < thr) {
            // replace-root sift-down on max-heap of size kk
            int e = 0;
            for (;;) {
                const int l = 2 * e + 1;
                if (l >= kk) break;
                const int r = l + 1;
                const float dl = sd[l * 256 + t];
                const float dr = (r < kk) ? sd[r * 256 + t] : -FLT_BIG;
                int c; float dc;
                if (dr > dl) { c = r; dc = dr; } else { c = l; dc = dl; }
                if (dc <= d) break;
                sd[e * 256 + t] = dc; si[e * 256 + t] = si[c * 256 + t];
                e = c;
            }
            sd[e * 256 + t] = d; si[e * 256 + t] = (unsigned short)m;
            thr = sd[t];
        }
    }

    // per-thread insertion sort ascending
    for (int i = 1; i < kk; ++i) {
        const float key = sd[i * 256 + t];
        const unsigned short ki = si[i * 256 + t];
        int e = i - 1;
        while (e >= 0 && sd[e * 256 + t] > key) {
            sd[(e + 1) * 256 + t] = sd[e * 256 + t];
            si[(e + 1) * 256 + t] = si[e * 256 + t];
            --e;
        }
        sd[(e + 1) * 256 + t] = key; si[(e + 1) * 256 + t] = ki;
    }

    __syncthreads();

    if (slice == 0) {
        // 4-way merge of sorted slice lists at threads t..t+3
        int h0 = 0, h1 = 0, h2 = 0, h3 = 0;
        float v0 = sd[t], v1 = sd[t + 1], v2 = sd[t + 2], v3 = sd[t + 3];
        const int obase = ((b * N + n) << 5) + (list ? k0 : 0);
        for (int i = 0; i < kk; ++i) {
            const float m01 = fminf(v0, v1); const int s01 = (v1 < v0) ? 1 : 0;
            const float m23 = fminf(v2, v3); const int s23 = (v3 < v2) ? 3 : 2;
            const int s = (m23 < m01) ? s23 : s01;
            int hs = (s == 0) ? h0 : (s == 1) ? h1 : (s == 2) ? h2 : h3;
            const int midx = si[hs * 256 + t + s];
            ++hs;
            const float nv = (hs < kk) ? sd[hs * 256 + t + s] : FLT_BIG;
            if (s == 0) { h0 = hs; v0 = nv; }
            else if (s == 1) { h1 = hs; v1 = nv; }
            else if (s == 2) { h2 = hs; v2 = nv; }
            else { h3 = hs; v3 = nv; }

            const float px = rb[midx], py = rb[N + midx], pz = rb[2 * N + midx];
            const float rx = px - qx, ry = py - qy, rz = pz - qz;
            const float dist = sqrtf(rx * rx + ry * ry + rz * rz);
            feat[obase + i] = make_float4(rx, ry, rz, dist);
        }
        if (list == 0) newp[b * N + n] = make_float4(qx, qy, qz, 0.f);
    }
}

// ---------------------------------------------------------------------------
// K2: conv1 + per-group (4 groups of 8ch) sum/sumsq accumulation.
// ---------------------------------------------------------------------------
__global__ __launch_bounds__(256) void conv1_stats_kernel(
    const float4* __restrict__ feat, const float* __restrict__ w1,
    const float* __restrict__ b1, float* __restrict__ stats1, int N)
{
    const int t = threadIdx.x;
    const size_t p = (size_t)blockIdx.x * 256 + t;
    const int b = (int)(p / ((size_t)N * 32));
    const float4 f = feat[p];
    float v[8] = {0, 0, 0, 0, 0, 0, 0, 0};   // 4 sums, 4 sumsqs
#pragma unroll
    for (int c = 0; c < 32; ++c) {
        const float4 w = ((const float4*)w1)[c];
        const float y = b1[c] + w.x * f.x + w.y * f.y + w.z * f.z + w.w * f.w;
        v[c >> 3] += y;
        v[4 + (c >> 3)] = fmaf(y, y, v[4 + (c >> 3)]);
    }
#pragma unroll
    for (int i = 0; i < 8; ++i) {
        float x = v[i];
#pragma unroll
        for (int o = 32; o; o >>= 1) x += __shfl_down(x, o);
        v[i] = x;
    }
    __shared__ float sacc[8];
    if (t < 8) sacc[t] = 0.f;
    __syncthreads();
    if ((t & 63) == 0) {
#pragma unroll
        for (int i = 0; i < 8; ++i) atomicAdd(&sacc[i], v[i]);
    }
    __syncthreads();
    if (t < 8) atomicAdd(&stats1[b * 8 + t], sacc[t]);
}

// ---------------------------------------------------------------------------
// finalize GN stats: mu, rstd per (b, group)
// ---------------------------------------------------------------------------
__global__ void finalize_gn_kernel(const float* __restrict__ stats,
                                   float* __restrict__ fin, int total, int gpb,
                                   float inv_cnt)
{
    const int i = threadIdx.x + blockIdx.x * blockDim.x;
    if (i >= total) return;
    const int b = i / gpb, g = i - b * gpb;
    const float S = stats[b * 2 * gpb + g];
    const float Q = stats[b * 2 * gpb + gpb + g];
    const float mu = S * inv_cnt;
    const float var = Q * inv_cnt - mu * mu;
    fin[i * 2] = mu;
    fin[i * 2 + 1] = rsqrtf(var + 1e-5f);
}

// ---------------------------------------------------------------------------
// K4/K6a: conv1+gn1+relu -> conv2 with lane = output channel (w2 row in
// registers, h broadcast via per-wave LDS tile). MODE 0: accumulate gn2
// stats. MODE 1: apply gn2+relu, channel-max -> scores.
// ---------------------------------------------------------------------------
template <int MODE>
__global__ __launch_bounds__(256) void conv2_pass_kernel(
    const float4* __restrict__ feat,
    const float* __restrict__ w1, const float* __restrict__ b1,
    const float* __restrict__ gn1w, const float* __restrict__ gn1b,
    const float* __restrict__ fin1,
    const float* __restrict__ w2, const float* __restrict__ b2,
    const float* __restrict__ gn2w, const float* __restrict__ gn2b,
    const float* __restrict__ fin2,
    float* __restrict__ stats2, float* __restrict__ scores, int N)
{
    const int t = threadIdx.x, lane = t & 63, wv = t >> 6;
    const int bpb = (N * 32) / 512;                 // blocks per sample
    const int b = blockIdx.x / bpb;
    const int pblock = (blockIdx.x - b * bpb) * 512;
    const size_t pbase = (size_t)b * N * 32 + pblock + wv * 128;

    const int c1 = lane & 31;
    const float4 w1r = ((const float4*)w1)[c1];
    const float b1c = b1[c1];
    const int g1 = c1 >> 3;
    const float mu1 = fin1[(b * 4 + g1) * 2], rs1 = fin1[(b * 4 + g1) * 2 + 1];
    const float sc1 = rs1 * gn1w[c1];
    const float sh1 = gn1b[c1] - mu1 * sc1;

    const int c2 = lane;
    float w2r[32];
#pragma unroll
    for (int jj = 0; jj < 8; ++jj) {
        const float4 v = ((const float4*)w2)[c2 * 8 + jj];
        w2r[jj * 4] = v.x; w2r[jj * 4 + 1] = v.y;
        w2r[jj * 4 + 2] = v.z; w2r[jj * 4 + 3] = v.w;
    }
    const float b2c = b2[c2];
    float sc2 = 0.f, sh2 = 0.f;
    if (MODE == 1) {
        const int g2 = c2 >> 3;
        const float mu2 = fin2[(b * 8 + g2) * 2], rs2 = fin2[(b * 8 + g2) * 2 + 1];
        sc2 = rs2 * gn2w[c2];
        sh2 = gn2b[c2] - mu2 * sc2;
    }

    __shared__ float hbuf[4][64];
    float gsum = 0.f, gsq = 0.f;
    const int pt = lane >> 5;

    for (int it = 0; it < 64; ++it) {
        const size_t p = pbase + it * 2;
        // conv1 + gn1 + relu: half-wave per point, lane = channel
        const float4 f = feat[p + pt];
        const float y = b1c + w1r.x * f.x + w1r.y * f.y + w1r.z * f.z + w1r.w * f.w;
        const float h = fmaxf(0.f, fmaf(y, sc1, sh1));
        hbuf[wv][pt * 32 + c1] = h;   // same-wave LDS: in-order, no barrier
        // conv2: all 64 lanes = 64 output channels, h broadcast from LDS
        float za = b2c, zb = b2c;
#pragma unroll
        for (int jj = 0; jj < 32; ++jj) za = fmaf(w2r[jj], hbuf[wv][jj], za);
#pragma unroll
        for (int jj = 0; jj < 32; ++jj) zb = fmaf(w2r[jj], hbuf[wv][32 + jj], zb);
        if (MODE == 0) {
            gsum += za + zb;
            gsq = fmaf(za, za, gsq);
            gsq = fmaf(zb, zb, gsq);
        } else {
            float sa = fmaxf(0.f, fmaf(za, sc2, sh2));
            float sb = fmaxf(0.f, fmaf(zb, sc2, sh2));
#pragma unroll
            for (int o = 32; o; o >>= 1) {
                sa = fmaxf(sa, __shfl_xor(sa, o));
                sb = fmaxf(sb, __shfl_xor(sb, o));
            }
            if (lane == 0) { scores[p] = sa; scores[p + 1] = sb; }
        }
    }
    if (MODE == 0) {
        // reduce within 8-lane channel groups, stage in LDS, one atomic set/block
#pragma unroll
        for (int o = 4; o; o >>= 1) {
            gsum += __shfl_down(gsum, o);
            gsq += __shfl_down(gsq, o);
        }
        __shared__ float sacc[16];
        if (t < 16) sacc[t] = 0.f;
        __syncthreads();
        if ((lane & 7) == 0) {
            atomicAdd(&sacc[lane >> 3], gsum);
            atomicAdd(&sacc[8 + (lane >> 3)], gsq);
        }
        __syncthreads();
        if (t < 16) atomicAdd(&stats2[b * 16 + t], sacc[t]);
    }
}

// ---------------------------------------------------------------------------
// K6b: softmax over k + weighted sum of neighbor coords (q + resi).
// ---------------------------------------------------------------------------
__global__ __launch_bounds__(256) void final_kernel(
    const float* __restrict__ scores, const float4* __restrict__ feat,
    const float4* __restrict__ newp, float* __restrict__ out, int N)
{
    const int idx = blockIdx.x * 256 + threadIdx.x;   // b*N + n
    const int b = idx / N, n = idx - b * N;
    const float4* sp = (const float4*)(scores + (size_t)idx * 32);
    float s[32];
#pragma unroll
    for (int j2 = 0; j2 < 8; ++j2) {
        const float4 v = sp[j2];
        s[j2 * 4] = v.x; s[j2 * 4 + 1] = v.y; s[j2 * 4 + 2] = v.z; s[j2 * 4 + 3] = v.w;
    }
    float m = s[0];
#pragma unroll
    for (int i = 1; i < 32; ++i) m = fmaxf(m, s[i]);
    float sum = 0.f;
#pragma unroll
    for (int i = 0; i < 32; ++i) { s[i] = __expf(s[i] - m); sum += s[i]; }
    const float4 q = newp[idx];
    float ax = 0.f, ay = 0.f, az = 0.f;
    const float4* fp = feat + (size_t)idx * 32;
#pragma unroll
    for (int i = 0; i < 32; ++i) {
        const float4 f = fp[i];
        ax = fmaf(s[i], q.x + f.x, ax);
        ay = fmaf(s[i], q.y + f.y, ay);
        az = fmaf(s[i], q.z + f.z, az);
    }
    const float inv = 1.f / sum;
    out[(b * 3 + 0) * N + n] = ax * inv;
    out[(b * 3 + 1) * N + n] = ay * inv;
    out[(b * 3 + 2) * N + n] = az * inv;
}

// ---------------------------------------------------------------------------
extern "C" void kernel_launch(void* const* d_in, const int* in_sizes, int n_in,
                              void* d_out, int out_size, void* d_ws, size_t ws_size,
                              hipStream_t stream)
{
    const float* p0   = (const float*)d_in[0];
    const float* p1   = (const float*)d_in[1];
    const float* wt   = (const float*)d_in[3];
    const int*   perm = (const int*)d_in[4];
    const float* w1   = (const float*)d_in[5];
    const float* b1   = (const float*)d_in[6];
    const float* gn1w = (const float*)d_in[7];
    const float* gn1b = (const float*)d_in[8];
    const float* w2   = (const float*)d_in[9];
    const float* b2   = (const float*)d_in[10];
    const float* gn2w = (const float*)d_in[11];
    const float* gn2b = (const float*)d_in[12];
    float* out = (float*)d_out;

    const int B = in_sizes[3] / 2;
    const int N = in_sizes[0] / (3 * B);

    // workspace layout
    char* ws = (char*)d_ws;
    float4* feat = (float4*)ws;
    size_t off = (size_t)B * N * 32 * sizeof(float4);
    float4* newp = (float4*)(ws + off);       off += (size_t)B * N * sizeof(float4);
    float* scores = (float*)(ws + off);       off += (size_t)B * N * 32 * sizeof(float);
    float* stats1 = (float*)(ws + off);       // B*8
    float* fin1   = stats1 + B * 8;           // B*8  (mu,rstd per b*4 groups)
    float* stats2 = fin1 + B * 8;             // B*16
    float* fin2   = stats2 + B * 16;          // B*16
    const size_t stats_bytes = (size_t)B * 48 * sizeof(float);

    hipMemsetAsync(stats1, 0, stats_bytes, stream);

    const float inv_cnt = 1.f / (8.f * (float)N * 32.f);

    knn_kernel<<<B * (N / 32), 256, 0, stream>>>(p0, p1, wt, perm, feat, newp, N);

    conv1_stats_kernel<<<(B * N * 32) / 256, 256, 0, stream>>>(feat, w1, b1, stats1, N);
    finalize_gn_kernel<<<(B * 4 + 63) / 64, 64, 0, stream>>>(stats1, fin1, B * 4, 4, inv_cnt);

    conv2_pass_kernel<0><<<(B * N * 32) / 512, 256, 0, stream>>>(
        feat, w1, b1, gn1w, gn1b, fin1, w2, b2, gn2w, gn2b, fin2, stats2, scores, N);
    finalize_gn_kernel<<<(B * 8 + 63) / 64, 64, 0, stream>>>(stats2, fin2, B * 8, 8, inv_cnt);

    conv2_pass_kernel<1><<<(B * N * 32) / 512, 256, 0, stream>>>(
        feat, w1, b1, gn1w, gn1b, fin1, w2, b2, gn2w, gn2b, fin2, stats2, scores, N);

    final_kernel<<<(B * N) / 256, 256, 0, stream>>>(scores, feat, newp, out, N);
}